// Round 2
// baseline (161.044 us; speedup 1.0000x reference)
//
#include <hip/hip_runtime.h>
#include <hip/hip_bf16.h>

// Problem constants (from reference): N=4,B=8,T=2,E=1024,H=16,D=64,S=2048,L=1024
#define NB_  32
#define T_   2
#define E_   1024
#define H_   16
#define D_   64
#define S_   2048
#define L_   1024
#define TOT_ (S_ + L_ + T_)   // 3074
#define ROWS_ 64              // NB*T token rows

// ---------------------------------------------------------------------------
// QKV projection: out[64][3072] = hidden[64][1024] @ Wcat^T + bias
// grid = 192 blocks (16 cols each), block = 256 threads (4 waves).
// lane = token row r; wave handles 4 output columns; hidden chunks staged
// transposed in LDS (stride 65 -> conflict-free); W read wave-uniform.
// q stored transposed qT[e][r]; k_new/v_new stored [nb][h][t][d].
// ---------------------------------------------------------------------------
__global__ __launch_bounds__(256) void qkv_kernel(
    const float* __restrict__ hidden,
    const float* __restrict__ Wq, const float* __restrict__ bq,
    const float* __restrict__ Wk, const float* __restrict__ bk,
    const float* __restrict__ Wv, const float* __restrict__ bv,
    float* __restrict__ qT,      // [1024][64]
    float* __restrict__ knew,    // [NB][H][T][D]
    float* __restrict__ vnew)    // [NB][H][T][D]
{
    __shared__ float ldsT[128 * 65];
    const int tid  = threadIdx.x;
    const int wave = tid >> 6;
    const int lane = tid & 63;          // token row r
    const int eg0  = blockIdx.x * 16;   // global col base
    const int mat  = eg0 >> 10;         // 0=q 1=k 2=v
    int e_in0 = (eg0 & 1023) + wave * 4;
    e_in0 = __builtin_amdgcn_readfirstlane(e_in0);  // force SGPR

    const float* W    = (mat == 0) ? Wq : (mat == 1) ? Wk : Wv;
    const float* bias = (mat == 0) ? bq : (mat == 1) ? bk : bv;

    float acc[4] = {0.f, 0.f, 0.f, 0.f};

    for (int k0 = 0; k0 < 1024; k0 += 128) {
        __syncthreads();
        // stage hidden[0:64][k0:k0+128] transposed: ldsT[c][r]
        #pragma unroll
        for (int i = 0; i < 32; i++) {
            int f = i * 256 + tid;
            int r = f >> 7;
            int c = f & 127;
            ldsT[c * 65 + r] = hidden[r * 1024 + k0 + c];
        }
        __syncthreads();
        for (int kk = 0; kk < 128; kk += 4) {
            float h0 = ldsT[(kk + 0) * 65 + lane];
            float h1 = ldsT[(kk + 1) * 65 + lane];
            float h2 = ldsT[(kk + 2) * 65 + lane];
            float h3 = ldsT[(kk + 3) * 65 + lane];
            #pragma unroll
            for (int j = 0; j < 4; j++) {
                const float* wrow = W + (e_in0 + j) * 1024 + k0 + kk;
                acc[j] = fmaf(h0, wrow[0], acc[j]);
                acc[j] = fmaf(h1, wrow[1], acc[j]);
                acc[j] = fmaf(h2, wrow[2], acc[j]);
                acc[j] = fmaf(h3, wrow[3], acc[j]);
            }
        }
    }

    const int r = lane;
    #pragma unroll
    for (int j = 0; j < 4; j++) {
        int e_in = e_in0 + j;
        float val = acc[j] + bias[e_in];
        if (mat == 0) {
            qT[e_in * 64 + r] = val;                       // coalesced
        } else {
            int nb = r >> 1, t = r & 1, h = e_in >> 6, d = e_in & 63;
            float* dst = (mat == 1) ? knew : vnew;
            dst[((nb * H_ + h) * T_ + t) * D_ + d] = val;  // scatter, tiny
        }
    }
}

// ---------------------------------------------------------------------------
// Attention: grid = NB*H = 512 blocks, 1024 threads = 64 groups of 16 lanes.
// Group streams every-64th KV position; lane owns 4 dims (float4 loads ->
// 1KB per wave-load, coalesced). Scores for both t via 4-step shfl_xor
// reduce; exp2 with log2(e) folded into q scale; no max subtraction
// (scores O(±4); mask added so -inf masking still works). Block merge in LDS.
// ---------------------------------------------------------------------------
__global__ __launch_bounds__(1024) void attn_kernel(
    const float* __restrict__ mask,   // [NB][TOT_]
    const float* __restrict__ pfx_k,  // [N][H][S][D]
    const float* __restrict__ pfx_v,
    const float* __restrict__ pk,     // [NB][H][L][D]
    const float* __restrict__ pv,
    const float* __restrict__ qT,     // [1024][64]
    const float* __restrict__ knew,   // [NB][H][T][D]
    const float* __restrict__ vnew,
    float* __restrict__ out)          // [NB][T][E]  (float32!)
{
    __shared__ float part_acc[64][128];  // [group][t*64+d]
    __shared__ float part_l[64][2];

    const int bid = blockIdx.x;
    const int nb  = bid >> 4;
    const int h   = bid & 15;
    const int n   = nb >> 3;

    const int tid = threadIdx.x;
    const int G   = tid >> 4;     // group 0..63
    const int l16 = tid & 15;
    const int d0  = l16 * 4;

    const float LOG2E = 1.4426950408889634f;
    const float qs = 0.125f * LOG2E;  // 1/sqrt(D) * log2(e)

    float qf0[4], qf1[4];
    #pragma unroll
    for (int j = 0; j < 4; j++) {
        const float* qb = qT + (h * 64 + d0 + j) * 64 + nb * 2;
        qf0[j] = qb[0] * qs;
        qf1[j] = qb[1] * qs;
    }

    const float* pfxk_b = pfx_k + ((n  * H_ + h) * (size_t)S_) * D_;
    const float* pfxv_b = pfx_v + ((n  * H_ + h) * (size_t)S_) * D_;
    const float* pk_b   = pk    + ((nb * H_ + h) * (size_t)L_) * D_;
    const float* pv_b   = pv    + ((nb * H_ + h) * (size_t)L_) * D_;
    const float* kn_b   = knew  + (nb * H_ + h) * (T_ * D_);
    const float* vn_b   = vnew  + (nb * H_ + h) * (T_ * D_);
    const float* mrow   = mask + nb * TOT_;

    float l0 = 0.f, l1 = 0.f;
    float a0[4] = {0.f, 0.f, 0.f, 0.f};
    float a1[4] = {0.f, 0.f, 0.f, 0.f};

    for (int p = G; p < TOT_; p += 64) {
        const float* kp;
        const float* vp;
        if (p < S_)           { kp = pfxk_b + p * D_;              vp = pfxv_b + p * D_; }
        else if (p < S_ + L_) { kp = pk_b + (p - S_) * D_;         vp = pv_b + (p - S_) * D_; }
        else                  { kp = kn_b + (p - S_ - L_) * D_;    vp = vn_b + (p - S_ - L_) * D_; }

        float4 kf = *reinterpret_cast<const float4*>(kp + d0);
        float s0 = qf0[0] * kf.x + qf0[1] * kf.y + qf0[2] * kf.z + qf0[3] * kf.w;
        float s1 = qf1[0] * kf.x + qf1[1] * kf.y + qf1[2] * kf.z + qf1[3] * kf.w;
        #pragma unroll
        for (int off = 1; off < 16; off <<= 1) {
            s0 += __shfl_xor(s0, off, 64);
            s1 += __shfl_xor(s1, off, 64);
        }
        float mC = mrow[p] * LOG2E;
        float e0 = exp2f(s0 + mC);
        float e1 = exp2f(s1 + mC);
        l0 += e0;
        l1 += e1;
        float4 vf = *reinterpret_cast<const float4*>(vp + d0);
        a0[0] += e0 * vf.x; a0[1] += e0 * vf.y; a0[2] += e0 * vf.z; a0[3] += e0 * vf.w;
        a1[0] += e1 * vf.x; a1[1] += e1 * vf.y; a1[2] += e1 * vf.z; a1[3] += e1 * vf.w;
    }

    if (l16 == 0) { part_l[G][0] = l0; part_l[G][1] = l1; }
    #pragma unroll
    for (int j = 0; j < 4; j++) {
        part_acc[G][d0 + j]      = a0[j];
        part_acc[G][64 + d0 + j] = a1[j];
    }
    __syncthreads();

    if (tid < 128) {
        int t = tid >> 6, d = tid & 63;
        float s = 0.f, l = 0.f;
        for (int g = 0; g < 64; g++) {
            s += part_acc[g][t * 64 + d];
            l += part_l[g][t];
        }
        out[(nb * 2 + t) * 1024 + h * 64 + d] = s / l;
    }
}

extern "C" void kernel_launch(void* const* d_in, const int* in_sizes, int n_in,
                              void* d_out, int out_size, void* d_ws, size_t ws_size,
                              hipStream_t stream) {
    const float* hidden = (const float*)d_in[0];
    const float* mask   = (const float*)d_in[1];
    const float* pfxk   = (const float*)d_in[2];
    const float* pfxv   = (const float*)d_in[3];
    const float* pk     = (const float*)d_in[4];
    const float* pv     = (const float*)d_in[5];
    const float* Wq     = (const float*)d_in[6];
    const float* bq     = (const float*)d_in[7];
    const float* Wk     = (const float*)d_in[8];
    const float* bk     = (const float*)d_in[9];
    const float* Wv     = (const float*)d_in[10];
    const float* bv     = (const float*)d_in[11];

    float* qT   = (float*)d_ws;          // 1024*64
    float* knew = qT + 65536;            // NB*H*T*D
    float* vnew = knew + 65536;

    qkv_kernel<<<192, 256, 0, stream>>>(hidden, Wq, bq, Wk, bk, Wv, bv,
                                        qT, knew, vnew);
    attn_kernel<<<512, 1024, 0, stream>>>(mask, pfxk, pfxv, pk, pv,
                                          qT, knew, vnew,
                                          (float*)d_out);
}